// Round 5
// baseline (231.139 us; speedup 1.0000x reference)
//
#include <hip/hip_runtime.h>
#include <math.h>

#define NB 16384
#define LH 50
#define D  64

typedef _Float16 half2v __attribute__((ext_vector_type(2)));
typedef _Float16 half8  __attribute__((ext_vector_type(8)));
typedef float    f32x16 __attribute__((ext_vector_type(16)));
typedef unsigned int u32;

#define MFMA(a, b, c) __builtin_amdgcn_mfma_f32_32x32x16_f16((a), (b), (c), 0, 0, 0)

// ---- fragment facts (32x32x16, verified m74/m101 + R3/R4 pass) ----
// A[m][k]: m=lane&31, k=(lane>>5)*8+j (8 contiguous k per lane)
// B[k][n]: n=lane&31, k=(lane>>5)*8+j
// C/D:     col=lane&31, row=(reg&3)+8*(reg>>2)+4*(lane>>5)

__device__ __forceinline__ u32 pack2(float a, float b) {
    half2v h; h[0] = (_Float16)a; h[1] = (_Float16)b;
    return __builtin_bit_cast(u32, h);
}
__device__ __forceinline__ half8 mk8(u32 a, u32 b, u32 c, u32 d) {
    uint4 t = make_uint4(a, b, c, d);
    return __builtin_bit_cast(half8, t);
}
__device__ __forceinline__ half8 cvt8(const float* __restrict__ p) {
    float4 u = *(const float4*)p;
    float4 v = *(const float4*)(p + 4);
    return mk8(pack2(u.x, u.y), pack2(u.z, u.w), pack2(v.x, v.y), pack2(v.z, v.w));
}

// relu + f16-pack + lane^32 exchange: one C tile -> two B-frags (k-halves) for
// the NEXT transposed GEMM (contraction over this tile's 32 rows).
__device__ __forceinline__ void xform_tile(const f32x16& t, int hv, half8& f0, half8& f1) {
    u32 p[8], rp[8];
    #pragma unroll
    for (int q = 0; q < 8; ++q) p[q] = pack2(fmaxf(t[2*q], 0.f), fmaxf(t[2*q+1], 0.f));
    #pragma unroll
    for (int q = 0; q < 8; ++q) rp[q] = (u32)__shfl_xor((int)p[q], 32, 64);
    f0 = hv ? mk8(rp[2], rp[3], p[2], p[3]) : mk8(p[0], p[1], rp[0], rp[1]);
    f1 = hv ? mk8(rp[6], rp[7], p[6], p[7]) : mk8(p[4], p[5], rp[4], rp[5]);
}

// bias tile (same for both nt tiles of a given mt) from the permuted table
__device__ __forceinline__ f32x16 ldbias(const float* __restrict__ tbf, int hv, int mt) {
    const float4* p = (const float4*)tbf + hv*8 + mt*4;
    f32x16 r;
    #pragma unroll
    for (int q = 0; q < 4; ++q) {
        float4 v = p[q];
        r[4*q] = v.x; r[4*q+1] = v.y; r[4*q+2] = v.z; r[4*q+3] = v.w;
    }
    return r;
}

// ================= K1: weight/bias reorder into ws =================
// ws halves: w1f[2][8][64][8] | w2f[2][4][64][8] | wa1lowf | wa1upf | wa2f
// then f32 @ byte 49152: b1p[64] b2p[64] ba1p[64] ba2p[64] wa3p[64]
__global__ void uv_prep(const float* __restrict__ w1, const float* __restrict__ w2,
                        const float* __restrict__ wa1, const float* __restrict__ wa2,
                        const float* __restrict__ b1, const float* __restrict__ b2,
                        const float* __restrict__ ba1, const float* __restrict__ ba2,
                        const float* __restrict__ wa3,
                        _Float16* __restrict__ wsh, float* __restrict__ tbf) {
    const int idx = blockIdx.x * 256 + threadIdx.x;   // grid 96 -> idx < 24576
    const int j = idx & 7, lane = (idx >> 3) & 63;
    const int hv = lane >> 5, m31 = lane & 31;
    float v;
    if (idx < 8192)       { const int ks = (idx >> 9) & 7, mt = (idx >> 12) & 1;
        v = w1 [(ks*16 + hv*8 + j)*64 + mt*32 + m31]; }
    else if (idx < 12288) { const int ks = (idx >> 9) & 3, mt = (idx >> 11) & 1;
        v = w2 [(ks*16 + hv*8 + j)*64 + mt*32 + m31]; }
    else if (idx < 16384) { const int ks = (idx >> 9) & 3, mt = (idx >> 11) & 1;
        v = wa1[(ks*16 + hv*8 + j)*64 + mt*32 + m31]; }
    else if (idx < 20480) { const int ks = (idx >> 9) & 3, mt = (idx >> 11) & 1;
        v = wa1[(64 + ks*16 + hv*8 + j)*64 + mt*32 + m31]; }
    else                  { const int ks = (idx >> 9) & 3, mt = (idx >> 11) & 1;
        v = wa2[(ks*16 + hv*8 + j)*64 + mt*32 + m31]; }
    wsh[idx] = (_Float16)v;

    if (blockIdx.x == 0 && threadIdx.x < 64) {
        const int t = threadIdx.x;
        const int thv = t >> 5, r = t & 31, mt = r >> 4, i = r & 15;
        const int feat = mt*32 + (i & 3) + 8*(i >> 2) + 4*thv;
        tbf[t]       = b1[feat];
        tbf[64 + t]  = b2[feat];
        tbf[128 + t] = ba1[feat];
        tbf[192 + t] = ba2[feat];
        tbf[256 + t] = wa3[feat];
    }
}

// ================= K2: fused forward, one wave per node =================
// No LDS, no __syncthreads: weight frags read straight from wsh (L1/L2-hot,
// coalesced dwordx4); LDS pipe reserved for the xform shuffles.
__global__ __launch_bounds__(256) void uv_main(
    const int*   __restrict__ nodes,
    const int*   __restrict__ huv,
    const int*   __restrict__ hr,
    const float* __restrict__ v2e,
    const float* __restrict__ u2e,
    const float* __restrict__ r2e,
    const _Float16* __restrict__ wsh,
    const float* __restrict__ tbf,
    float*       __restrict__ out) {
    const int tid = threadIdx.x;
    const int lane = tid & 63, wid = tid >> 6;
    const int b = blockIdx.x * 4 + wid;
    const int n = lane & 31, hv = lane >> 5;

    // weight frag fetch: section base (in halves) + frag index
    #define G8(base, f) (*(const half8*)(wsh + (base) + (size_t)((f)*64 + lane)*8))

    // ---- token rows (tok = nt*32+n; rows 50..63 duplicate row 49, masked later)
    const int t1  = (32 + n < LH) ? 32 + n : LH - 1;
    const int iv0 = __builtin_nontemporal_load(huv + b*LH + n);
    const int iv1 = __builtin_nontemporal_load(huv + b*LH + t1);
    const int ir0 = __builtin_nontemporal_load(hr + b*LH + n);
    const int ir1 = __builtin_nontemporal_load(hr + b*LH + t1);
    const float* xv0 = v2e + (size_t)iv0 * D + hv*8;
    const float* xv1 = v2e + (size_t)iv1 * D + hv*8;
    const float* xr0 = r2e + (size_t)ir0 * D + hv*8;
    const float* xr1 = r2e + (size_t)ir1 * D + hv*8;

    // ---- u-broadcast B-frags for att1's K-extension (u row wave-uniform -> s_load)
    const float* urow = u2e + (size_t)nodes[b] * D + hv*8;
    half8 uf[4];
    #pragma unroll
    for (int ks = 0; ks < 4; ++ks) uf[ks] = cvt8(urow + ks*16);

    // ======== layer 1 (transposed): H[feat][tok] = W1^T @ X^T + b1
    // first K-step takes the bias tile directly as MFMA C (no reg broadcast)
    f32x16 a00, a01, a10, a11;
    {
        const f32x16 bc0 = ldbias(tbf, hv, 0), bc1 = ldbias(tbf, hv, 1);
        half8 bf0 = cvt8(xv0), bf1 = cvt8(xv1);
        half8 w0 = G8(0, 0), w1f = G8(0, 8);
        a00 = MFMA(w0, bf0, bc0);  a01 = MFMA(w0, bf1, bc0);
        a10 = MFMA(w1f, bf0, bc1); a11 = MFMA(w1f, bf1, bc1);
    }
    #pragma unroll
    for (int ks = 1; ks < 8; ++ks) {
        const float* p0 = (ks < 4) ? xv0 + ks*16 : xr0 + (ks - 4)*16;
        const float* p1 = (ks < 4) ? xv1 + ks*16 : xr1 + (ks - 4)*16;
        half8 bf0 = cvt8(p0), bf1 = cvt8(p1);
        half8 w0 = G8(0, ks), w1f = G8(0, 8 + ks);
        a00 = MFMA(w0, bf0, a00);  a01 = MFMA(w0, bf1, a01);
        a10 = MFMA(w1f, bf0, a10); a11 = MFMA(w1f, bf1, a11);
    }
    half8 hf[2][4];                          // relu+exchange -> B-frags of H
    xform_tile(a00, hv, hf[0][0], hf[0][1]); xform_tile(a01, hv, hf[1][0], hf[1][1]);
    xform_tile(a10, hv, hf[0][2], hf[0][3]); xform_tile(a11, hv, hf[1][2], hf[1][3]);

    // ======== layer 2: O[feat][tok] = W2^T @ H + b2
    {
        const f32x16 bc0 = ldbias(tbf + 64, hv, 0), bc1 = ldbias(tbf + 64, hv, 1);
        half8 w0 = G8(8192, 0), w1f = G8(8192, 4);
        a00 = MFMA(w0, hf[0][0], bc0);  a01 = MFMA(w0, hf[1][0], bc0);
        a10 = MFMA(w1f, hf[0][0], bc1); a11 = MFMA(w1f, hf[1][0], bc1);
    }
    #pragma unroll
    for (int ks = 1; ks < 4; ++ks) {
        half8 w0 = G8(8192, ks), w1f = G8(8192, 4 + ks);
        a00 = MFMA(w0, hf[0][ks], a00);  a01 = MFMA(w0, hf[1][ks], a01);
        a10 = MFMA(w1f, hf[0][ks], a10); a11 = MFMA(w1f, hf[1][ks], a11);
    }
    half8 of[2][4];                          // O frags: feed att1 AND the epilogue
    xform_tile(a00, hv, of[0][0], of[0][1]); xform_tile(a01, hv, of[1][0], of[1][1]);
    xform_tile(a10, hv, of[0][2], of[0][3]); xform_tile(a11, hv, of[1][2], of[1][3]);

    // ======== att1: A1 = relu(Wa1low^T @ O + Wa1up^T @ u_bcast + ba1)
    {
        const f32x16 bc0 = ldbias(tbf + 128, hv, 0), bc1 = ldbias(tbf + 128, hv, 1);
        half8 w0 = G8(12288, 0), w1f = G8(12288, 4);
        a00 = MFMA(w0, of[0][0], bc0);  a01 = MFMA(w0, of[1][0], bc0);
        a10 = MFMA(w1f, of[0][0], bc1); a11 = MFMA(w1f, of[1][0], bc1);
    }
    #pragma unroll
    for (int ks = 1; ks < 4; ++ks) {
        half8 w0 = G8(12288, ks), w1f = G8(12288, 4 + ks);
        a00 = MFMA(w0, of[0][ks], a00);  a01 = MFMA(w0, of[1][ks], a01);
        a10 = MFMA(w1f, of[0][ks], a10); a11 = MFMA(w1f, of[1][ks], a11);
    }
    #pragma unroll
    for (int ks = 0; ks < 4; ++ks) {         // u K-extension (same B for both nt)
        half8 w0 = G8(16384, ks), w1f = G8(16384, 4 + ks);
        a00 = MFMA(w0, uf[ks], a00);  a01 = MFMA(w0, uf[ks], a01);
        a10 = MFMA(w1f, uf[ks], a10); a11 = MFMA(w1f, uf[ks], a11);
    }
    half8 af[2][4];
    xform_tile(a00, hv, af[0][0], af[0][1]); xform_tile(a01, hv, af[1][0], af[1][1]);
    xform_tile(a10, hv, af[0][2], af[0][3]); xform_tile(a11, hv, af[1][2], af[1][3]);

    // ======== att2 + logits (mt sequential; bias via MFMA C)
    float lg0 = 0.f, lg1 = 0.f;
    #pragma unroll
    for (int mt = 0; mt < 2; ++mt) {
        f32x16 c0, c1;
        {
            const f32x16 bc = ldbias(tbf + 192, hv, mt);
            half8 w = G8(20480, mt*4 + 0);
            c0 = MFMA(w, af[0][0], bc);
            c1 = MFMA(w, af[1][0], bc);
        }
        #pragma unroll
        for (int ks = 1; ks < 4; ++ks) {
            half8 w = G8(20480, mt*4 + ks);
            c0 = MFMA(w, af[0][ks], c0);
            c1 = MFMA(w, af[1][ks], c1);
        }
        #pragma unroll
        for (int q = 0; q < 4; ++q) {
            float4 w3 = ((const float4*)(tbf + 256))[hv*8 + mt*4 + q];
            lg0 += fmaxf(c0[4*q], 0.f)*w3.x + fmaxf(c0[4*q+1], 0.f)*w3.y
                 + fmaxf(c0[4*q+2], 0.f)*w3.z + fmaxf(c0[4*q+3], 0.f)*w3.w;
            lg1 += fmaxf(c1[4*q], 0.f)*w3.x + fmaxf(c1[4*q+1], 0.f)*w3.y
                 + fmaxf(c1[4*q+2], 0.f)*w3.z + fmaxf(c1[4*q+3], 0.f)*w3.w;
        }
    }
    // combine feat-halves across lane^32: each lane now holds logits of tokens n, n+32
    lg0 += __shfl_xor(lg0, 32, 64);
    lg1 += __shfl_xor(lg1, 32, 64);
    if (32 + n >= LH) lg1 = -1e30f;

    // ---- softmax over 64 tokens (butterfly over the 32 token-lanes)
    float mx = fmaxf(lg0, lg1);
    #pragma unroll
    for (int off = 16; off >= 1; off >>= 1) mx = fmaxf(mx, __shfl_xor(mx, off, 64));
    const float e0 = __expf(lg0 - mx);
    const float e1 = __expf(lg1 - mx);       // masked token: exp(-huge)=0
    float s = e0 + e1;
    #pragma unroll
    for (int off = 16; off >= 1; off >>= 1) s += __shfl_xor(s, off, 64);
    const float at0 = e0 / s, at1 = e1 / s;

    // ======== epilogue: out[feat] = sum_tok att[tok]*O[feat][tok]
    float cur[32];
    #pragma unroll
    for (int ks = 0; ks < 4; ++ks)
        #pragma unroll
        for (int j = 0; j < 8; ++j)
            cur[ks*8 + j] = at0 * (float)of[0][ks][j] + at1 * (float)of[1][ks][j];
    // recursive-halving reduce-scatter over the 32 token-lanes (5 levels, 31 shfl)
    #pragma unroll
    for (int k = 0; k < 5; ++k) {
        const int d = 1 << k, mybit = (lane >> k) & 1, half = 16 >> k;
        #pragma unroll
        for (int j2 = 0; j2 < 16; ++j2) {
            if (j2 < half) {
                float sel  = mybit ? cur[2*j2]     : cur[2*j2 + 1];
                float got  = __shfl_xor(sel, d, 64);
                float keep = mybit ? cur[2*j2 + 1] : cur[2*j2];
                cur[j2] = keep + got;
            }
        }
    }
    // lane owns feat = [bits: lane4 lane3 | hv | lane2 lane1 lane0]
    const int feat = ((lane >> 3) & 3)*16 + hv*8 + (lane & 7);
    __builtin_nontemporal_store(cur[0], out + (size_t)b * D + feat);
    #undef G8
}

extern "C" void kernel_launch(void* const* d_in, const int* in_sizes, int n_in,
                              void* d_out, int out_size, void* d_ws, size_t ws_size,
                              hipStream_t stream) {
    const int*   nodes      = (const int*)  d_in[0];
    const int*   history_uv = (const int*)  d_in[1];
    const int*   history_r  = (const int*)  d_in[2];
    const float* v2e        = (const float*)d_in[3];
    const float* u2e        = (const float*)d_in[4];
    const float* r2e        = (const float*)d_in[5];
    const float* w1         = (const float*)d_in[6];
    const float* b1         = (const float*)d_in[7];
    const float* w2         = (const float*)d_in[8];
    const float* b2         = (const float*)d_in[9];
    const float* wa1        = (const float*)d_in[10];
    const float* ba1        = (const float*)d_in[11];
    const float* wa2        = (const float*)d_in[12];
    const float* ba2        = (const float*)d_in[13];
    const float* wa3        = (const float*)d_in[14];
    float* out = (float*)d_out;

    _Float16* wsh = (_Float16*)d_ws;
    float*    tbf = (float*)((char*)d_ws + 49152);

    uv_prep<<<96, 256, 0, stream>>>(w1, w2, wa1, wa2, b1, b2, ba1, ba2, wa3, wsh, tbf);
    uv_main<<<NB / 4, 256, 0, stream>>>(nodes, history_uv, history_r,
                                        v2e, u2e, r2e, wsh, tbf, out);
}

// Round 6
// 219.573 us; speedup vs baseline: 1.0527x; 1.0527x over previous
//
#include <hip/hip_runtime.h>
#include <math.h>

#define NB 16384
#define LH 50
#define D  64

typedef _Float16 half2v __attribute__((ext_vector_type(2)));
typedef _Float16 half8  __attribute__((ext_vector_type(8)));
typedef float    f32x16 __attribute__((ext_vector_type(16)));
typedef unsigned int u32;

#define MFMA(a, b, c) __builtin_amdgcn_mfma_f32_32x32x16_f16((a), (b), (c), 0, 0, 0)

// ---- fragment facts (32x32x16, verified m74/m101 + R3..R5 pass) ----
// A[m][k]: m=lane&31, k=(lane>>5)*8+j (8 contiguous k per lane)
// B[k][n]: n=lane&31, k=(lane>>5)*8+j
// C/D:     col=lane&31, row=(reg&3)+8*(reg>>2)+4*(lane>>5)

__device__ __forceinline__ u32 pack2(float a, float b) {
    half2v h; h[0] = (_Float16)a; h[1] = (_Float16)b;
    return __builtin_bit_cast(u32, h);
}
__device__ __forceinline__ half8 mk8(u32 a, u32 b, u32 c, u32 d) {
    uint4 t = make_uint4(a, b, c, d);
    return __builtin_bit_cast(half8, t);
}
__device__ __forceinline__ half8 cvt8(const float* __restrict__ p) {
    float4 u = *(const float4*)p;
    float4 v = *(const float4*)(p + 4);
    return mk8(pack2(u.x, u.y), pack2(u.z, u.w), pack2(v.x, v.y), pack2(v.z, v.w));
}
__device__ __forceinline__ half8 cvt8v(float4 u, float4 v) {
    return mk8(pack2(u.x, u.y), pack2(u.z, u.w), pack2(v.x, v.y), pack2(v.z, v.w));
}

// relu + f16-pack + lane^32 exchange: one C tile -> two B-frags (k-halves) for
// the NEXT transposed GEMM (contraction over this tile's 32 rows).
__device__ __forceinline__ void xform_tile(const f32x16& t, int hv, half8& f0, half8& f1) {
    u32 p[8], rp[8];
    #pragma unroll
    for (int q = 0; q < 8; ++q) p[q] = pack2(fmaxf(t[2*q], 0.f), fmaxf(t[2*q+1], 0.f));
    #pragma unroll
    for (int q = 0; q < 8; ++q) rp[q] = (u32)__shfl_xor((int)p[q], 32, 64);
    f0 = hv ? mk8(rp[2], rp[3], p[2], p[3]) : mk8(p[0], p[1], rp[0], rp[1]);
    f1 = hv ? mk8(rp[6], rp[7], p[6], p[7]) : mk8(p[4], p[5], rp[4], rp[5]);
}

// bias tile (same for both nt tiles of a given mt) from the permuted table
__device__ __forceinline__ f32x16 ldbias(const float* __restrict__ tbf, int hv, int mt) {
    const float4* p = (const float4*)tbf + hv*8 + mt*4;
    f32x16 r;
    #pragma unroll
    for (int q = 0; q < 4; ++q) {
        float4 v = p[q];
        r[4*q] = v.x; r[4*q+1] = v.y; r[4*q+2] = v.z; r[4*q+3] = v.w;
    }
    return r;
}

// ================= K1: weight/bias reorder into ws =================
// ws halves: w1f[2][8][64][8] | w2f[2][4][64][8] | wa1lowf | wa1upf | wa2f
// then f32 @ byte 49152: b1p[64] b2p[64] ba1p[64] ba2p[64] wa3p[64]
__global__ void uv_prep(const float* __restrict__ w1, const float* __restrict__ w2,
                        const float* __restrict__ wa1, const float* __restrict__ wa2,
                        const float* __restrict__ b1, const float* __restrict__ b2,
                        const float* __restrict__ ba1, const float* __restrict__ ba2,
                        const float* __restrict__ wa3,
                        _Float16* __restrict__ wsh, float* __restrict__ tbf) {
    const int idx = blockIdx.x * 256 + threadIdx.x;   // grid 96 -> idx < 24576
    const int j = idx & 7, lane = (idx >> 3) & 63;
    const int hv = lane >> 5, m31 = lane & 31;
    float v;
    if (idx < 8192)       { const int ks = (idx >> 9) & 7, mt = (idx >> 12) & 1;
        v = w1 [(ks*16 + hv*8 + j)*64 + mt*32 + m31]; }
    else if (idx < 12288) { const int ks = (idx >> 9) & 3, mt = (idx >> 11) & 1;
        v = w2 [(ks*16 + hv*8 + j)*64 + mt*32 + m31]; }
    else if (idx < 16384) { const int ks = (idx >> 9) & 3, mt = (idx >> 11) & 1;
        v = wa1[(ks*16 + hv*8 + j)*64 + mt*32 + m31]; }
    else if (idx < 20480) { const int ks = (idx >> 9) & 3, mt = (idx >> 11) & 1;
        v = wa1[(64 + ks*16 + hv*8 + j)*64 + mt*32 + m31]; }
    else                  { const int ks = (idx >> 9) & 3, mt = (idx >> 11) & 1;
        v = wa2[(ks*16 + hv*8 + j)*64 + mt*32 + m31]; }
    wsh[idx] = (_Float16)v;

    if (blockIdx.x == 0 && threadIdx.x < 64) {
        const int t = threadIdx.x;
        const int thv = t >> 5, r = t & 31, mt = r >> 4, i = r & 15;
        const int feat = mt*32 + (i & 3) + 8*(i >> 2) + 4*thv;
        tbf[t]       = b1[feat];
        tbf[64 + t]  = b2[feat];
        tbf[128 + t] = ba1[feat];
        tbf[192 + t] = ba2[feat];
        tbf[256 + t] = wa3[feat];
    }
}

// ================= K2: fused forward, ONE WAVE per block/node =================
// v2e rows are staged coalesced (8 lanes x 16B per row-chunk) through a
// wave-private 8.3 KB LDS buffer (plane-per-piece, stride 65 -> conflict-free
// stride-1 reads, even-banked writes). No __syncthreads anywhere.
__global__ __launch_bounds__(64) void uv_main(
    const int*   __restrict__ nodes,
    const int*   __restrict__ huv,
    const int*   __restrict__ hr,
    const float* __restrict__ v2e,
    const float* __restrict__ u2e,
    const float* __restrict__ r2e,
    const _Float16* __restrict__ wsh,
    const float* __restrict__ tbf,
    float*       __restrict__ out) {
    __shared__ float4 stage[520];            // 8 planes x 65 units (16B each)
    const int lane = threadIdx.x;
    const int b = blockIdx.x;
    const int n = lane & 31, hv = lane >> 5;

    // weight frag fetch: section base (in halves) + frag index
    #define G8(base, f) (*(const half8*)(wsh + (base) + (size_t)((f)*64 + lane)*8))

    // ---- staging indices: lane loads piece qq of rows t = j*8+tg, j=0..7
    const int tg = lane >> 3;                // row-in-group 0..7
    const int qq = lane & 7;                 // 16B piece within 128B chunk
    int rowid[8];
    #pragma unroll
    for (int j = 0; j < 8; ++j) {
        int t = j*8 + tg; if (t > LH-1) t = LH-1;
        rowid[j] = huv[b*LH + t];
    }
    // issue both 8 KB chunks' loads up-front (coalesced: 8 lanes span 128B/row)
    float4 c1[8], c2[8];
    #pragma unroll
    for (int j = 0; j < 8; ++j)
        c1[j] = *(const float4*)(v2e + (size_t)rowid[j]*D + qq*4);
    #pragma unroll
    for (int j = 0; j < 8; ++j)
        c2[j] = *(const float4*)(v2e + (size_t)rowid[j]*D + 32 + qq*4);

    // ---- r2e token gathers stay direct (only 5 distinct rows -> line-shared)
    const int t1  = (32 + n < LH) ? 32 + n : LH - 1;
    const int ir0 = __builtin_nontemporal_load(hr + b*LH + n);
    const int ir1 = __builtin_nontemporal_load(hr + b*LH + t1);
    const float* xr0 = r2e + (size_t)ir0 * D + hv*8;
    const float* xr1 = r2e + (size_t)ir1 * D + hv*8;

    // ---- u-broadcast B-frags for att1's K-extension (u row wave-uniform -> s_load)
    const float* urow = u2e + (size_t)nodes[b] * D + hv*8;
    half8 uf[4];
    #pragma unroll
    for (int ks = 0; ks < 4; ++ks) uf[ks] = cvt8(urow + ks*16);

    // ======== layer 1 (transposed): H[feat][tok] = W1^T @ X^T + b1
    f32x16 a00, a01, a10, a11;
    // stage chunk1 (pieces 0..7 = ks 0,1)
    #pragma unroll
    for (int j = 0; j < 8; ++j) stage[qq*65 + j*8 + tg] = c1[j];
    {   // ks = 0 (bias as MFMA C)
        const f32x16 bc0 = ldbias(tbf, hv, 0), bc1 = ldbias(tbf, hv, 1);
        const int p0 = hv*2;
        half8 bf0 = cvt8v(stage[p0*65 + n],      stage[(p0+1)*65 + n]);
        half8 bf1 = cvt8v(stage[p0*65 + 32 + n], stage[(p0+1)*65 + 32 + n]);
        half8 w0 = G8(0, 0), w1f = G8(0, 8);
        a00 = MFMA(w0, bf0, bc0);  a01 = MFMA(w0, bf1, bc0);
        a10 = MFMA(w1f, bf0, bc1); a11 = MFMA(w1f, bf1, bc1);
    }
    {   // ks = 1
        const int p0 = 4 + hv*2;
        half8 bf0 = cvt8v(stage[p0*65 + n],      stage[(p0+1)*65 + n]);
        half8 bf1 = cvt8v(stage[p0*65 + 32 + n], stage[(p0+1)*65 + 32 + n]);
        half8 w0 = G8(0, 1), w1f = G8(0, 9);
        a00 = MFMA(w0, bf0, a00);  a01 = MFMA(w0, bf1, a01);
        a10 = MFMA(w1f, bf0, a10); a11 = MFMA(w1f, bf1, a11);
    }
    // stage chunk2 (pieces 8..15 = ks 2,3) into the same planes (WAR: DS in-order)
    #pragma unroll
    for (int j = 0; j < 8; ++j) stage[qq*65 + j*8 + tg] = c2[j];
    #pragma unroll
    for (int ks = 2; ks < 4; ++ks) {
        const int p0 = (ks - 2)*4 + hv*2;
        half8 bf0 = cvt8v(stage[p0*65 + n],      stage[(p0+1)*65 + n]);
        half8 bf1 = cvt8v(stage[p0*65 + 32 + n], stage[(p0+1)*65 + 32 + n]);
        half8 w0 = G8(0, ks), w1f = G8(0, 8 + ks);
        a00 = MFMA(w0, bf0, a00);  a01 = MFMA(w0, bf1, a01);
        a10 = MFMA(w1f, bf0, a10); a11 = MFMA(w1f, bf1, a11);
    }
    #pragma unroll
    for (int ks = 4; ks < 8; ++ks) {          // rating half: direct gathers
        half8 bf0 = cvt8(xr0 + (ks - 4)*16);
        half8 bf1 = cvt8(xr1 + (ks - 4)*16);
        half8 w0 = G8(0, ks), w1f = G8(0, 8 + ks);
        a00 = MFMA(w0, bf0, a00);  a01 = MFMA(w0, bf1, a01);
        a10 = MFMA(w1f, bf0, a10); a11 = MFMA(w1f, bf1, a11);
    }
    half8 hf[2][4];                          // relu+exchange -> B-frags of H
    xform_tile(a00, hv, hf[0][0], hf[0][1]); xform_tile(a01, hv, hf[1][0], hf[1][1]);
    xform_tile(a10, hv, hf[0][2], hf[0][3]); xform_tile(a11, hv, hf[1][2], hf[1][3]);

    // ======== layer 2: O[feat][tok] = W2^T @ H + b2
    {
        const f32x16 bc0 = ldbias(tbf + 64, hv, 0), bc1 = ldbias(tbf + 64, hv, 1);
        half8 w0 = G8(8192, 0), w1f = G8(8192, 4);
        a00 = MFMA(w0, hf[0][0], bc0);  a01 = MFMA(w0, hf[1][0], bc0);
        a10 = MFMA(w1f, hf[0][0], bc1); a11 = MFMA(w1f, hf[1][0], bc1);
    }
    #pragma unroll
    for (int ks = 1; ks < 4; ++ks) {
        half8 w0 = G8(8192, ks), w1f = G8(8192, 4 + ks);
        a00 = MFMA(w0, hf[0][ks], a00);  a01 = MFMA(w0, hf[1][ks], a01);
        a10 = MFMA(w1f, hf[0][ks], a10); a11 = MFMA(w1f, hf[1][ks], a11);
    }
    half8 of[2][4];                          // O frags: feed att1 AND the epilogue
    xform_tile(a00, hv, of[0][0], of[0][1]); xform_tile(a01, hv, of[1][0], of[1][1]);
    xform_tile(a10, hv, of[0][2], of[0][3]); xform_tile(a11, hv, of[1][2], of[1][3]);

    // ======== att1: A1 = relu(Wa1low^T @ O + Wa1up^T @ u_bcast + ba1)
    {
        const f32x16 bc0 = ldbias(tbf + 128, hv, 0), bc1 = ldbias(tbf + 128, hv, 1);
        half8 w0 = G8(12288, 0), w1f = G8(12288, 4);
        a00 = MFMA(w0, of[0][0], bc0);  a01 = MFMA(w0, of[1][0], bc0);
        a10 = MFMA(w1f, of[0][0], bc1); a11 = MFMA(w1f, of[1][0], bc1);
    }
    #pragma unroll
    for (int ks = 1; ks < 4; ++ks) {
        half8 w0 = G8(12288, ks), w1f = G8(12288, 4 + ks);
        a00 = MFMA(w0, of[0][ks], a00);  a01 = MFMA(w0, of[1][ks], a01);
        a10 = MFMA(w1f, of[0][ks], a10); a11 = MFMA(w1f, of[1][ks], a11);
    }
    #pragma unroll
    for (int ks = 0; ks < 4; ++ks) {         // u K-extension (same B for both nt)
        half8 w0 = G8(16384, ks), w1f = G8(16384, 4 + ks);
        a00 = MFMA(w0, uf[ks], a00);  a01 = MFMA(w0, uf[ks], a01);
        a10 = MFMA(w1f, uf[ks], a10); a11 = MFMA(w1f, uf[ks], a11);
    }
    half8 af[2][4];
    xform_tile(a00, hv, af[0][0], af[0][1]); xform_tile(a01, hv, af[1][0], af[1][1]);
    xform_tile(a10, hv, af[0][2], af[0][3]); xform_tile(a11, hv, af[1][2], af[1][3]);

    // ======== att2 + logits (mt sequential; bias via MFMA C)
    float lg0 = 0.f, lg1 = 0.f;
    #pragma unroll
    for (int mt = 0; mt < 2; ++mt) {
        f32x16 c0, c1v;
        {
            const f32x16 bc = ldbias(tbf + 192, hv, mt);
            half8 w = G8(20480, mt*4 + 0);
            c0  = MFMA(w, af[0][0], bc);
            c1v = MFMA(w, af[1][0], bc);
        }
        #pragma unroll
        for (int ks = 1; ks < 4; ++ks) {
            half8 w = G8(20480, mt*4 + ks);
            c0  = MFMA(w, af[0][ks], c0);
            c1v = MFMA(w, af[1][ks], c1v);
        }
        #pragma unroll
        for (int q = 0; q < 4; ++q) {
            float4 w3 = ((const float4*)(tbf + 256))[hv*8 + mt*4 + q];
            lg0 += fmaxf(c0[4*q], 0.f)*w3.x + fmaxf(c0[4*q+1], 0.f)*w3.y
                 + fmaxf(c0[4*q+2], 0.f)*w3.z + fmaxf(c0[4*q+3], 0.f)*w3.w;
            lg1 += fmaxf(c1v[4*q], 0.f)*w3.x + fmaxf(c1v[4*q+1], 0.f)*w3.y
                 + fmaxf(c1v[4*q+2], 0.f)*w3.z + fmaxf(c1v[4*q+3], 0.f)*w3.w;
        }
    }
    // combine feat-halves across lane^32: each lane now holds logits of tokens n, n+32
    lg0 += __shfl_xor(lg0, 32, 64);
    lg1 += __shfl_xor(lg1, 32, 64);
    if (32 + n >= LH) lg1 = -1e30f;

    // ---- softmax over 64 tokens (butterfly over the 32 token-lanes)
    float mx = fmaxf(lg0, lg1);
    #pragma unroll
    for (int off = 16; off >= 1; off >>= 1) mx = fmaxf(mx, __shfl_xor(mx, off, 64));
    const float e0 = __expf(lg0 - mx);
    const float e1 = __expf(lg1 - mx);       // masked token: exp(-huge)=0
    float s = e0 + e1;
    #pragma unroll
    for (int off = 16; off >= 1; off >>= 1) s += __shfl_xor(s, off, 64);
    const float at0 = e0 / s, at1 = e1 / s;

    // ======== epilogue: out[feat] = sum_tok att[tok]*O[feat][tok]
    float cur[32];
    #pragma unroll
    for (int ks = 0; ks < 4; ++ks)
        #pragma unroll
        for (int j = 0; j < 8; ++j)
            cur[ks*8 + j] = at0 * (float)of[0][ks][j] + at1 * (float)of[1][ks][j];
    // recursive-halving reduce-scatter over the 32 token-lanes (5 levels, 31 shfl)
    #pragma unroll
    for (int k = 0; k < 5; ++k) {
        const int d = 1 << k, mybit = (lane >> k) & 1, half = 16 >> k;
        #pragma unroll
        for (int j2 = 0; j2 < 16; ++j2) {
            if (j2 < half) {
                float sel  = mybit ? cur[2*j2]     : cur[2*j2 + 1];
                float got  = __shfl_xor(sel, d, 64);
                float keep = mybit ? cur[2*j2 + 1] : cur[2*j2];
                cur[j2] = keep + got;
            }
        }
    }
    // lane owns feat = [bits: lane4 lane3 | hv | lane2 lane1 lane0]
    const int feat = ((lane >> 3) & 3)*16 + hv*8 + (lane & 7);
    __builtin_nontemporal_store(cur[0], out + (size_t)b * D + feat);
    #undef G8
}

extern "C" void kernel_launch(void* const* d_in, const int* in_sizes, int n_in,
                              void* d_out, int out_size, void* d_ws, size_t ws_size,
                              hipStream_t stream) {
    const int*   nodes      = (const int*)  d_in[0];
    const int*   history_uv = (const int*)  d_in[1];
    const int*   history_r  = (const int*)  d_in[2];
    const float* v2e        = (const float*)d_in[3];
    const float* u2e        = (const float*)d_in[4];
    const float* r2e        = (const float*)d_in[5];
    const float* w1         = (const float*)d_in[6];
    const float* b1         = (const float*)d_in[7];
    const float* w2         = (const float*)d_in[8];
    const float* b2         = (const float*)d_in[9];
    const float* wa1        = (const float*)d_in[10];
    const float* ba1        = (const float*)d_in[11];
    const float* wa2        = (const float*)d_in[12];
    const float* ba2        = (const float*)d_in[13];
    const float* wa3        = (const float*)d_in[14];
    float* out = (float*)d_out;

    _Float16* wsh = (_Float16*)d_ws;
    float*    tbf = (float*)((char*)d_ws + 49152);

    uv_prep<<<96, 256, 0, stream>>>(w1, w2, wa1, wa2, b1, b2, ba1, ba2, wa3, wsh, tbf);
    uv_main<<<NB, 64, 0, stream>>>(nodes, history_uv, history_r,
                                   v2e, u2e, r2e, wsh, tbf, out);
}